// Round 6
// baseline (168.709 us; speedup 1.0000x reference)
//
#include <hip/hip_runtime.h>

// BiAlignLayer collapses algebraically:
//   softmax rows/cols sum to 1  =>  mean over seq of weighted_i / weighted_j
//   equal mean(i) / mean(j) exactly.  With u = mean_l(i) - mean_m(j):
//   out = 0.5 * ( relu(u@W + b) + relu(-u@W + b) )
// Stage 1: streaming reduce (i - j) over L  (~128 MB read).
//   R6: read path pinned at ~4.2 TB/s regardless of occupancy (R2), order
//   (R3), nt (R4: 3.0->4.2), wave-side depth (R5 neutral). Write path does
//   6.6 TB/s. Hypothesis: cap lives in the L1->VGPR load-return path.
//   Experiment: LDS-DMA (global_load_lds width=16) wave-private double
//   buffer, raw s_waitcnt vmcnt(2) pipeline, no barriers in the K-loop.
// Stage 2: [B,D] x [D,NN] matvec + bias + dual relu (unchanged control)

#define BB 32
#define LL 1024
#define DD 512
#define NNN 512
#define SPLIT 16
#define ROWS (LL / SPLIT)          // 64 rows per chunk
#define NF4 (ROWS * DD / 4)        // 8192 f4 per chunk per stream
#define T1 1024                    // stage1 block size (16 waves)
#define NWIN 8                     // NF4 / T1 windows

typedef float f4 __attribute__((ext_vector_type(4)));

__device__ __forceinline__ void gl_lds16(const void* g, void* l) {
    __builtin_amdgcn_global_load_lds(
        (const __attribute__((address_space(1))) void*)g,
        (__attribute__((address_space(3))) void*)l, 16, 0, 0);
}

__global__ __launch_bounds__(T1) void bialign_stage1(
    const float* __restrict__ gi, const float* __restrict__ gj,
    float* __restrict__ part) {
    // 64 KB: staging (wave-private 4 KB regions), reused for final reduce
    __shared__ f4 lds4[4096];
    char* lds = (char*)lds4;

    const int blk = blockIdx.x;            // b*SPLIT + s
    const int b = blk >> 4;
    const int s = blk & (SPLIT - 1);
    const size_t base = (size_t)b * LL * DD + (size_t)s * ROWS * DD;
    const f4* i4 = (const f4*)(gi + base);
    const f4* j4 = (const f4*)(gj + base);
    const int t = threadIdx.x;
    const int wv = t >> 6;                 // wave id 0..15
    const int lane = t & 63;

    // wave-private region: 4 KB = 2 bufs x (1 KB i + 1 KB j)
    char* wbase = lds + wv * 4096;

    // window w: wave wv covers f4 indices w*1024 + wv*64 + lane
    // (1024 % 128 == 0 -> thread t's d-phase is constant: t mod 128)
    #define ISSUE(w, p)                                                  \
        do {                                                             \
            const int gidx = (w) * T1 + wv * 64 + lane;                  \
            gl_lds16(i4 + gidx, wbase + (p) * 2048);                     \
            gl_lds16(j4 + gidx, wbase + (p) * 2048 + 1024);              \
        } while (0)

    ISSUE(0, 0);
    ISSUE(1, 1);

    f4 acc0 = 0.f, acc1 = 0.f;
    #pragma unroll
    for (int w = 0; w < NWIN; ++w) {
        // vmcnt(2): oldest window's 2 LDS-DMA loads complete; keep the
        // prefetched window's 2 in flight. Tail window waits vmcnt(0).
        // imm: lgkmcnt=15 (no wait), expcnt=7 (no wait), vmcnt in [3:0].
        if (w == NWIN - 1) __builtin_amdgcn_s_waitcnt(0x0F70);
        else               __builtin_amdgcn_s_waitcnt(0x0F72);
        const int p = w & 1;
        f4 av = *(const f4*)(wbase + p * 2048 + lane * 16);
        f4 cv = *(const f4*)(wbase + p * 2048 + 1024 + lane * 16);
        if (w & 1) acc1 += av - cv; else acc0 += av - cv;
        if (w < NWIN - 2) ISSUE(w + 2, p);
    }
    acc0 += acc1;
    #undef ISSUE

    // Cross-wave reduce. Thread t's f4-phase == t mod 128; slot t in a
    // [8 groups][128 f4] layout is exactly sm4[t].
    __syncthreads();                       // staging data dead; reuse LDS
    f4* sm4 = lds4;
    sm4[t] = acc0;
    __syncthreads();
    if (t < 128) {
        f4 s0 = sm4[t];
        #pragma unroll
        for (int g = 1; g < 8; ++g) s0 += sm4[g * 128 + t];
        ((f4*)(part + (size_t)blk * DD))[t] = s0;
    }
}

// Stage 2: grid (B, 4) blocks of 256. Block (b, ns) computes out[b, ns*128 .. +127].
// Threads t<128 accumulate d=[0,256) for col ns*128+t; t>=128 accumulate d=[256,512)
// for col ns*128+(t-128); combine in LDS.
__global__ __launch_bounds__(256) void bialign_stage2(
    const float* __restrict__ part, const float* __restrict__ W,
    const float* __restrict__ bias, float* __restrict__ out) {
    const int b = blockIdx.x;
    const int ns = blockIdx.y;
    const int t = threadIdx.x;              // 256

    __shared__ float u[DD];
    __shared__ float psum[256];
    // u[d] = (1/L) * sum over SPLIT partials
    for (int d = t; d < DD; d += 256) {
        const float* p = part + (size_t)b * SPLIT * DD + d;
        float sum = 0.f;
        #pragma unroll
        for (int k = 0; k < SPLIT; ++k) sum += p[(size_t)k * DD];
        u[d] = sum * (1.0f / (float)LL);
    }
    __syncthreads();

    const int col = ns * 128 + (t & 127);
    const int d0 = (t >> 7) * 256;          // 0 or 256
    float acc = 0.f;
    #pragma unroll 8
    for (int d = 0; d < 256; ++d) {
        acc = fmaf(u[d0 + d], W[(size_t)(d0 + d) * NNN + col], acc);
    }
    psum[t] = acc;
    __syncthreads();
    if (t < 128) {
        const float dot = psum[t] + psum[t + 128];
        const float bb = bias[col];
        const float r = 0.5f * (fmaxf(dot + bb, 0.f) + fmaxf(bb - dot, 0.f));
        out[(size_t)b * NNN + col] = r;
    }
}

extern "C" void kernel_launch(void* const* d_in, const int* in_sizes, int n_in,
                              void* d_out, int out_size, void* d_ws, size_t ws_size,
                              hipStream_t stream) {
    const float* gi   = (const float*)d_in[0];   // [B, L, D]
    const float* gj   = (const float*)d_in[1];   // [B, L, D]
    const float* W    = (const float*)d_in[2];   // [D, NN]
    const float* bias = (const float*)d_in[3];   // [NN]
    float* out = (float*)d_out;                  // [B, NN]
    float* part = (float*)d_ws;                  // B*SPLIT*D floats = 1 MB

    bialign_stage1<<<BB * SPLIT, T1, 0, stream>>>(gi, gj, part);
    bialign_stage2<<<dim3(BB, 4), 256, 0, stream>>>(part, W, bias, out);
}

// Round 7
// 157.382 us; speedup vs baseline: 1.0720x; 1.0720x over previous
//
#include <hip/hip_runtime.h>

// BiAlignLayer collapses algebraically:
//   softmax rows/cols sum to 1  =>  mean over seq of weighted_i / weighted_j
//   equal mean(i) / mean(j) exactly.  With u = mean_l(i) - mean_m(j):
//   out = 0.5 * ( relu(u@W + b) + relu(-u@W + b) )
// Stage 1: streaming reduce (i - j) over L  (~128 MB read).
//   History: plain 3.0 TB/s -> nt 4.2 TB/s (R4); occupancy (R2), order (R3),
//   wave-depth (R5), LDS-DMA (R6) all neutral-or-worse. Write path does
//   6.6 TB/s. R7: test whether L2/L3 hit-service is the cap — inline-asm
//   global_load_dwordx4 sc0 sc1 nt (cache-bypass streaming loads), R5's
//   all-16-in-flight structure, pass-through s_waitcnt for correctness.
// Stage 2: [B,D] x [D,NN] matvec + bias + dual relu (unchanged control)

#define BB 32
#define LL 1024
#define DD 512
#define NNN 512
#define SPLIT 16
#define ROWS (LL / SPLIT)          // 64 rows per chunk
#define NVEC (ROWS * DD / 4)       // 8192 float4 per chunk per stream
#define T1 1024                    // stage1 block size
#define NWIN (NVEC / T1)           // 8 windows per stream

typedef float f4 __attribute__((ext_vector_type(4)));

__device__ __forceinline__ f4 load_bypass(const f4* p) {
    f4 r;
    asm volatile("global_load_dwordx4 %0, %1, off sc0 sc1 nt"
                 : "=v"(r) : "v"(p));
    return r;
}

__global__ __launch_bounds__(T1, 4) void bialign_stage1(
    const float* __restrict__ gi, const float* __restrict__ gj,
    float* __restrict__ part) {
    const int blk = blockIdx.x;            // b*SPLIT + s
    const int b = blk >> 4;                // / SPLIT
    const int s = blk & (SPLIT - 1);
    const size_t base = (size_t)b * LL * DD + (size_t)s * ROWS * DD;
    const f4* i4 = (const f4*)(gi + base);
    const f4* j4 = (const f4*)(gj + base);
    const int t = threadIdx.x;

    // All 16 independent cache-bypass loads in flight (256 B payload,
    // 64 VGPRs; launch_bounds(1024,4) -> 128 VGPR cap).
    f4 a[NWIN], c[NWIN];
    #pragma unroll
    for (int w = 0; w < NWIN; ++w) {
        a[w] = load_bypass(i4 + (size_t)w * T1 + t);
        c[w] = load_bypass(j4 + (size_t)w * T1 + t);
    }
    // Single drain; +v pass-through makes every use data-depend on the wait,
    // volatile ordering keeps it after the loads.
    asm volatile("s_waitcnt vmcnt(0)"
                 : "+v"(a[0]), "+v"(a[1]), "+v"(a[2]), "+v"(a[3]),
                   "+v"(a[4]), "+v"(a[5]), "+v"(a[6]), "+v"(a[7]),
                   "+v"(c[0]), "+v"(c[1]), "+v"(c[2]), "+v"(c[3]),
                   "+v"(c[4]), "+v"(c[5]), "+v"(c[6]), "+v"(c[7]));

    // Window stride = T1 f4 = 4096 floats == 0 mod 512 -> each thread's
    // d-phase is constant: phase(t) = (4t) mod 512; 8 phase-groups (t>>7).
    f4 acc0 = 0.f, acc1 = 0.f, acc2 = 0.f, acc3 = 0.f;
    #pragma unroll
    for (int w = 0; w < NWIN; w += 4) {
        acc0 += a[w + 0] - c[w + 0];
        acc1 += a[w + 1] - c[w + 1];
        acc2 += a[w + 2] - c[w + 2];
        acc3 += a[w + 3] - c[w + 3];
    }
    acc0 += acc1;
    acc2 += acc3;
    acc0 += acc2;

    // 8 phase-groups of 128 threads each -> LDS [8][512] floats (16 KB)
    __shared__ float sm[8 * DD];
    f4* sm4 = (f4*)sm;
    sm4[(t >> 7) * 128 + (t & 127)] = acc0;     // group g, slot p = t&127
    __syncthreads();
    if (t < 128) {
        f4 s0 = sm4[t];
        #pragma unroll
        for (int g = 1; g < 8; ++g) {
            s0 += sm4[g * 128 + t];
        }
        ((f4*)(part + (size_t)blk * DD))[t] = s0;
    }
}

// Stage 2: grid (B, 4) blocks of 256. Block (b, ns) computes out[b, ns*128 .. +127].
// Threads t<128 accumulate d=[0,256) for col ns*128+t; t>=128 accumulate d=[256,512)
// for col ns*128+(t-128); combine in LDS.
__global__ __launch_bounds__(256) void bialign_stage2(
    const float* __restrict__ part, const float* __restrict__ W,
    const float* __restrict__ bias, float* __restrict__ out) {
    const int b = blockIdx.x;
    const int ns = blockIdx.y;
    const int t = threadIdx.x;              // 256

    __shared__ float u[DD];
    __shared__ float psum[256];
    // u[d] = (1/L) * sum over SPLIT partials
    for (int d = t; d < DD; d += 256) {
        const float* p = part + (size_t)b * SPLIT * DD + d;
        float sum = 0.f;
        #pragma unroll
        for (int k = 0; k < SPLIT; ++k) sum += p[(size_t)k * DD];
        u[d] = sum * (1.0f / (float)LL);
    }
    __syncthreads();

    const int col = ns * 128 + (t & 127);
    const int d0 = (t >> 7) * 256;          // 0 or 256
    float acc = 0.f;
    #pragma unroll 8
    for (int d = 0; d < 256; ++d) {
        acc = fmaf(u[d0 + d], W[(size_t)(d0 + d) * NNN + col], acc);
    }
    psum[t] = acc;
    __syncthreads();
    if (t < 128) {
        const float dot = psum[t] + psum[t + 128];
        const float bb = bias[col];
        const float r = 0.5f * (fmaxf(dot + bb, 0.f) + fmaxf(bb - dot, 0.f));
        out[(size_t)b * NNN + col] = r;
    }
}

extern "C" void kernel_launch(void* const* d_in, const int* in_sizes, int n_in,
                              void* d_out, int out_size, void* d_ws, size_t ws_size,
                              hipStream_t stream) {
    const float* gi   = (const float*)d_in[0];   // [B, L, D]
    const float* gj   = (const float*)d_in[1];   // [B, L, D]
    const float* W    = (const float*)d_in[2];   // [D, NN]
    const float* bias = (const float*)d_in[3];   // [NN]
    float* out = (float*)d_out;                  // [B, NN]
    float* part = (float*)d_ws;                  // B*SPLIT*D floats = 1 MB

    bialign_stage1<<<BB * SPLIT, T1, 0, stream>>>(gi, gj, part);
    bialign_stage2<<<dim3(BB, 4), 256, 0, stream>>>(part, W, bias, out);
}